// Round 4
// baseline (265.373 us; speedup 1.0000x reference)
//
#include <hip/hip_runtime.h>
#include <hip/hip_bf16.h>
#include <math.h>

#define NQ 14
#define DIM 16384
#define NB 256
#define NH 1024
#define SPLITK 16
#define KCHUNK (DIM / SPLITK)   // 1024
#define BK 64

typedef __attribute__((ext_vector_type(8))) short bf16x8;
typedef __attribute__((ext_vector_type(4))) float f32x4;

// LDS swizzle for the state arrays: i + 5*(i>>5)  (injective, <=2-way banks)
#define SW(i) ((i) + 5 * ((i) >> 5))
#define SW_SIZE (DIM + 5 * (DIM / 32))   // 16384 + 2560 = 18944

// ---------------------------------------------------------------- QR helper
// Gram-Schmidt QR (double) -> Q with positive-real diag(R) == make_unitary(M)
template <int N>
__device__ void gs_qr(const float* Mre, const float* Mim, float* Uout) {
    double qre[N][N], qim[N][N];   // [col][row]
#pragma unroll
    for (int j = 0; j < N; j++) {
        double vr[N], vi[N];
#pragma unroll
        for (int r = 0; r < N; r++) { vr[r] = (double)Mre[r * N + j]; vi[r] = (double)Mim[r * N + j]; }
#pragma unroll
        for (int i = 0; i < N; i++) {
            if (i < j) {
                double rr = 0.0, ri = 0.0;
#pragma unroll
                for (int r = 0; r < N; r++) {
                    rr += qre[i][r] * vr[r] + qim[i][r] * vi[r];
                    ri += qre[i][r] * vi[r] - qim[i][r] * vr[r];
                }
#pragma unroll
                for (int r = 0; r < N; r++) {
                    vr[r] -= rr * qre[i][r] - ri * qim[i][r];
                    vi[r] -= rr * qim[i][r] + ri * qre[i][r];
                }
            }
        }
        double nn = 0.0;
#pragma unroll
        for (int r = 0; r < N; r++) nn += vr[r] * vr[r] + vi[r] * vi[r];
        double inv = 1.0 / sqrt(nn);
#pragma unroll
        for (int r = 0; r < N; r++) { qre[j][r] = vr[r] * inv; qim[j][r] = vi[r] * inv; }
    }
#pragma unroll
    for (int r = 0; r < N; r++)
#pragma unroll
        for (int j = 0; j < N; j++) {
            Uout[(r * N + j) * 2]     = (float)qre[j][r];
            Uout[(r * N + j) * 2 + 1] = (float)qim[j][r];
        }
}

// ---------------------------------------------------------------- kernel A
// blocks 0..NB-1: params = x @ w_pre^T + b_pre -> v vectors
// block NB: 2x2 QRs; block NB+1: 4x4 QRs
__global__ __launch_bounds__(256) void k_pre(const float* __restrict__ x,
                                             const float* __restrict__ w_pre,
                                             const float* __restrict__ b_pre,
                                             const float* __restrict__ sq_re,
                                             const float* __restrict__ sq_im,
                                             const float* __restrict__ ent_re,
                                             const float* __restrict__ ent_im,
                                             float* __restrict__ v_buf,
                                             float* __restrict__ sqU,
                                             float* __restrict__ entU) {
    const int b = blockIdx.x;
    const int t = threadIdx.x;
    if (b >= NB) {
        if (b == NB) {
            if (t < NQ) gs_qr<2>(sq_re + t * 4, sq_im + t * 4, sqU + t * 8);
        } else {
            if (t < NQ - 1) gs_qr<4>(ent_re + t * 16, ent_im + t * 16, entU + t * 32);
        }
        return;
    }
    __shared__ float red[28][4];

    float4 xs = ((const float4*)(x + (size_t)b * NH))[t];
    float acc[28];
#pragma unroll
    for (int j = 0; j < 28; j++) {
        float4 w = ((const float4*)(w_pre + (size_t)j * NH))[t];
        acc[j] = xs.x * w.x + xs.y * w.y + xs.z * w.z + xs.w * w.w;
    }
    int lane = t & 63, wv = t >> 6;
#pragma unroll
    for (int j = 0; j < 28; j++) {
        float a = acc[j];
#pragma unroll
        for (int o = 32; o > 0; o >>= 1) a += __shfl_down(a, o);
        if (lane == 0) red[j][wv] = a;
    }
    __syncthreads();
    if (t < NQ) {
        float p0 = red[2*t][0] + red[2*t][1] + red[2*t][2] + red[2*t][3] + b_pre[2*t];
        float p1 = red[2*t+1][0] + red[2*t+1][1] + red[2*t+1][2] + red[2*t+1][3] + b_pre[2*t+1];
        float c = cosf(p0 * 0.5f), s = sinf(p0 * 0.5f);
        float cp = cosf(p1), sp = sinf(p1);
        ((float4*)v_buf)[b * NQ + t] = make_float4(c, 0.f, cp * s, sp * s);
    }
}

// ---------------------------------------------------------------- kernel C
// Register-resident statevector: thread owns 16 amps (4 index bits).
// Ownership windows {0-3} -> {3-6} -> {6-9} -> {9-12} -> {10-13}; all 13
// two-qubit gates are register-local; 4 LDS transposes remap ownership.
//
// apply gate at window position I (bits I, I+1 of the register index)
#define APPLY_GATE(I, GP) do {                                                \
    float gr_[16], gi_[16];                                                   \
    _Pragma("unroll")                                                         \
    for (int m_ = 0; m_ < 16; m_++) { gr_[m_] = (GP)[2*m_]; gi_[m_] = (GP)[2*m_+1]; } \
    _Pragma("unroll")                                                         \
    for (int g_ = 0; g_ < 4; g_++) {                                          \
        const int base_ = (I)==0 ? (g_<<2) : ((I)==1 ? ((g_&1)|((g_>>1)<<3)) : g_); \
        float xr_[4], xi_[4];                                                 \
        _Pragma("unroll")                                                     \
        for (int c_ = 0; c_ < 4; c_++) { xr_[c_] = ar[base_+(c_<<(I))]; xi_[c_] = ai[base_+(c_<<(I))]; } \
        _Pragma("unroll")                                                     \
        for (int r_ = 0; r_ < 4; r_++) {                                      \
            float nr_ = 0.f, ni_ = 0.f;                                       \
            _Pragma("unroll")                                                 \
            for (int c_ = 0; c_ < 4; c_++) {                                  \
                nr_ += gr_[r_*4+c_]*xr_[c_] - gi_[r_*4+c_]*xi_[c_];           \
                ni_ += gr_[r_*4+c_]*xi_[c_] + gi_[r_*4+c_]*xr_[c_];           \
            }                                                                 \
            ar[base_+(r_<<(I))] = nr_; ai[base_+(r_<<(I))] = ni_;             \
        }                                                                     \
    }                                                                         \
} while (0)

#define IDX_W0(r) (((t) << 4) | (r))
#define IDX_W1(r) (((t) & 7) | ((r) << 3) | (((t) >> 3) << 7))
#define IDX_W2(r) (((t) & 63) | ((r) << 6) | (((t) >> 6) << 10))
#define IDX_W3(r) (((t) & 511) | ((r) << 9) | (((t) >> 9) << 13))
#define IDX_W4(r) ((t) | ((r) << 10))

#define TRANSPOSE(IDX_OLD, IDX_NEW) do {                                      \
    _Pragma("unroll")                                                         \
    for (int r_ = 0; r_ < 16; r_++) {                                         \
        int o_ = SW(IDX_OLD(r_));                                             \
        sre[o_] = ar[r_]; simg[o_] = ai[r_];                                  \
    }                                                                         \
    __syncthreads();                                                          \
    _Pragma("unroll")                                                         \
    for (int r_ = 0; r_ < 16; r_++) {                                         \
        int n_ = SW(IDX_NEW(r_));                                             \
        ar[r_] = sre[n_]; ai[r_] = simg[n_];                                  \
    }                                                                         \
} while (0)

extern __shared__ float smem[];
__global__ __launch_bounds__(1024) void k_state(const float* __restrict__ v_buf,
                                                const float* __restrict__ sqU,
                                                const float* __restrict__ entU,
                                                __hip_bfloat16* __restrict__ probs) {
    const int b = blockIdx.x, t = threadIdx.x;
    float* sre  = smem;                       // SW_SIZE
    float* simg = smem + SW_SIZE;             // SW_SIZE
    float* wloc = smem + 2 * SW_SIZE;         // 14*4
    float* g2   = wloc + NQ * 4;              // 13*32

    if (t < (NQ - 1) * 32) g2[t] = entU[t];
    if (t < NQ) {
        // w_q = U_q v_q  (fused single-qubit gates)
        float4 v = ((const float4*)v_buf)[b * NQ + t];
        const float* u = sqU + t * 8;
        float w0r = u[0]*v.x - u[1]*v.y + u[2]*v.z - u[3]*v.w;
        float w0i = u[0]*v.y + u[1]*v.x + u[2]*v.w + u[3]*v.z;
        float w1r = u[4]*v.x - u[5]*v.y + u[6]*v.z - u[7]*v.w;
        float w1i = u[4]*v.y + u[5]*v.x + u[6]*v.w + u[7]*v.z;
        wloc[t*4+0] = w0r; wloc[t*4+1] = w0i; wloc[t*4+2] = w1r; wloc[t*4+3] = w1i;
    }
    __syncthreads();

    // ---- initial product state, ownership W0 (bits 0..3 in registers)
    float ar[16], ai[16];
    {
        float cr = 1.f, ci = 0.f;       // product over qubits 4..13 (bits of t)
#pragma unroll
        for (int q = 4; q < 14; q++) {
            int bit = (t >> (q - 4)) & 1;
            float br = wloc[q*4 + 2*bit], bi = wloc[q*4 + 2*bit + 1];
            float nr = cr*br - ci*bi, ni = cr*bi + ci*br;
            cr = nr; ci = ni;
        }
        float p01r[4], p01i[4], p23r[4], p23i[4];
#pragma unroll
        for (int j = 0; j < 4; j++) {
            int b0 = j & 1, b1 = j >> 1;
            float a0r = wloc[0*4 + 2*b0], a0i = wloc[0*4 + 2*b0 + 1];
            float a1r = wloc[1*4 + 2*b1], a1i = wloc[1*4 + 2*b1 + 1];
            p01r[j] = a0r*a1r - a0i*a1i; p01i[j] = a0r*a1i + a0i*a1r;
            float a2r = wloc[2*4 + 2*b0], a2i = wloc[2*4 + 2*b0 + 1];
            float a3r = wloc[3*4 + 2*b1], a3i = wloc[3*4 + 2*b1 + 1];
            p23r[j] = a2r*a3r - a2i*a3i; p23i[j] = a2r*a3i + a2i*a3r;
        }
#pragma unroll
        for (int r = 0; r < 16; r++) {
            int lo = r & 3, hi2 = r >> 2;
            float tr = cr*p01r[lo] - ci*p01i[lo];
            float ti = cr*p01i[lo] + ci*p01r[lo];
            ar[r] = tr*p23r[hi2] - ti*p23i[hi2];
            ai[r] = tr*p23i[hi2] + ti*p23r[hi2];
        }
    }

    // ---- W0 {0,1,2,3}: gates 0,1,2
    APPLY_GATE(0, g2 + 0*32);
    APPLY_GATE(1, g2 + 1*32);
    APPLY_GATE(2, g2 + 2*32);
    TRANSPOSE(IDX_W0, IDX_W1);
    // ---- W1 {3,4,5,6}: gates 3,4,5
    APPLY_GATE(0, g2 + 3*32);
    APPLY_GATE(1, g2 + 4*32);
    APPLY_GATE(2, g2 + 5*32);
    __syncthreads();                 // protect previous reads before rewrite
    TRANSPOSE(IDX_W1, IDX_W2);
    // ---- W2 {6,7,8,9}: gates 6,7,8
    APPLY_GATE(0, g2 + 6*32);
    APPLY_GATE(1, g2 + 7*32);
    APPLY_GATE(2, g2 + 8*32);
    __syncthreads();
    TRANSPOSE(IDX_W2, IDX_W3);
    // ---- W3 {9,10,11,12}: gates 9,10,11
    APPLY_GATE(0, g2 + 9*32);
    APPLY_GATE(1, g2 + 10*32);
    APPLY_GATE(2, g2 + 11*32);
    __syncthreads();
    TRANSPOSE(IDX_W3, IDX_W4);
    // ---- W4 {10,11,12,13}: gate 12 at position (2,3)
    APPLY_GATE(2, g2 + 12*32);

    // ---- probs, ownership W4: idx = t | (r<<10)
#pragma unroll
    for (int r = 0; r < 16; r++) {
        float pr = ar[r]*ar[r] + ai[r]*ai[r];
        probs[(size_t)b * DIM + (r << 10) + t] = __float2bfloat16(pr);
    }
}

// ---------------------------------------------------------------- kernel D
// bf16 MFMA GEMM: part[z] = probs[bf16] @ w_post^T (B f32 -> bf16 in staging)
// 64x64 tile, BK=64, 4 waves (2x2), wave tile 32x32, split-K=16.
// grid (4,16,16) = 1024 blocks = 4 blocks/CU for memory-latency overlap.
__global__ __launch_bounds__(256) void k_gemm_mfma(const ushort* __restrict__ A,
                                                   const float* __restrict__ Bw,
                                                   float* __restrict__ part) {
    __shared__ ushort As[64 * 64];
    __shared__ ushort Bs[64 * 64];
    const int t = threadIdx.x;
    const int l = t & 63, wid = t >> 6;             // 4 waves
    const int wr = wid >> 1, wc = wid & 1;          // 2 x 2 waves
    const int bm0 = blockIdx.x * 64;
    const int hn0 = blockIdx.y * 64;
    const int k0  = blockIdx.z * KCHUNK;

    f32x4 acc[2][2];
#pragma unroll
    for (int m = 0; m < 2; m++)
#pragma unroll
        for (int n = 0; n < 2; n++) acc[m][n] = (f32x4){0.f, 0.f, 0.f, 0.f};

    const int srow = t >> 3;            // 0..31 (B staging row within issue)
    const int scol = (t & 7) * 8;       // staging col (elems)
    const int alr  = l >> 3;            // lane row within 8-row chunk
    const int alc  = (l & 7) * 8;       // lane col (elems)

    for (int kc = 0; kc < KCHUNK; kc += BK) {
        const int kbase = k0 + kc;
        // ---- A: bf16 via global_load_lds (16B/lane), 8 wave-issues of 8 rows
#pragma unroll
        for (int i = 0; i < 2; i++) {
            const int r0 = (i * 4 + wid) * 8;       // wave-uniform row base
            const ushort* gsrc = A + (size_t)(bm0 + r0 + alr) * DIM + kbase + alc;
            __builtin_amdgcn_global_load_lds(
                (const __attribute__((address_space(1))) unsigned int*)gsrc,
                (__attribute__((address_space(3))) unsigned int*)&As[r0 * 64],
                16, 0, 0);
        }
        // ---- B: f32 load -> bf16 cvt -> ds_write_b128, 2 issues x 32 rows
#pragma unroll
        for (int i = 0; i < 2; i++) {
            const int r = i * 32 + srow;
            const float* bsrc = Bw + (size_t)(hn0 + r) * DIM + kbase + scol;
            float4 b0 = *(const float4*)(bsrc);
            float4 b1 = *(const float4*)(bsrc + 4);
            union { ushort u[8]; bf16x8 v; } pk;
            __hip_bfloat16 h;
            h = __float2bfloat16(b0.x); pk.u[0] = *(ushort*)&h;
            h = __float2bfloat16(b0.y); pk.u[1] = *(ushort*)&h;
            h = __float2bfloat16(b0.z); pk.u[2] = *(ushort*)&h;
            h = __float2bfloat16(b0.w); pk.u[3] = *(ushort*)&h;
            h = __float2bfloat16(b1.x); pk.u[4] = *(ushort*)&h;
            h = __float2bfloat16(b1.y); pk.u[5] = *(ushort*)&h;
            h = __float2bfloat16(b1.z); pk.u[6] = *(ushort*)&h;
            h = __float2bfloat16(b1.w); pk.u[7] = *(ushort*)&h;
            *(bf16x8*)&Bs[r * 64 + scol] = pk.v;
        }
        __syncthreads();   // drains vmcnt (global_load_lds) + lgkmcnt (ds_write)
        // ---- compute: 2 k-steps of 32, 4 MFMAs per wave per k-step
#pragma unroll
        for (int kk = 0; kk < 2; kk++) {
            const int kcol = kk * 32 + (l >> 4) * 8;
            bf16x8 a[2], bb[2];
#pragma unroll
            for (int m = 0; m < 2; m++)
                a[m] = *(const bf16x8*)&As[(wr * 32 + m * 16 + (l & 15)) * 64 + kcol];
#pragma unroll
            for (int n = 0; n < 2; n++)
                bb[n] = *(const bf16x8*)&Bs[(wc * 32 + n * 16 + (l & 15)) * 64 + kcol];
#pragma unroll
            for (int m = 0; m < 2; m++)
#pragma unroll
                for (int n = 0; n < 2; n++)
                    acc[m][n] = __builtin_amdgcn_mfma_f32_16x16x32_bf16(
                        a[m], bb[n], acc[m][n], 0, 0, 0);
        }
        __syncthreads();
    }
    // ---- write f32 partials; C/D layout: col = lane&15, row = (lane>>4)*4 + j
    float* dst = part + (size_t)blockIdx.z * (NB * NH);
#pragma unroll
    for (int m = 0; m < 2; m++) {
        const int row = bm0 + wr * 32 + m * 16 + (l >> 4) * 4;
#pragma unroll
        for (int n = 0; n < 2; n++) {
            const int col = hn0 + wc * 32 + n * 16 + (l & 15);
#pragma unroll
            for (int j = 0; j < 4; j++)
                dst[(size_t)(row + j) * NH + col] = acc[m][n][j];
        }
    }
}

__global__ __launch_bounds__(256) void k_reduce(const float* __restrict__ part,
                                                const float* __restrict__ b_post,
                                                float* __restrict__ out) {
    int i = blockIdx.x * 256 + threadIdx.x;   // 0..262143
    float s = b_post[i & (NH - 1)];
#pragma unroll
    for (int z = 0; z < SPLITK; z++) s += part[(size_t)z * (NB * NH) + i];
    out[i] = s;
}

// ---------------------------------------------------------------- launch
extern "C" void kernel_launch(void* const* d_in, const int* in_sizes, int n_in,
                              void* d_out, int out_size, void* d_ws, size_t ws_size,
                              hipStream_t stream) {
    const float* x      = (const float*)d_in[0];
    const float* w_pre  = (const float*)d_in[1];
    const float* b_pre  = (const float*)d_in[2];
    const float* w_post = (const float*)d_in[3];
    const float* b_post = (const float*)d_in[4];
    const float* sq_re  = (const float*)d_in[5];
    const float* sq_im  = (const float*)d_in[6];
    const float* ent_re = (const float*)d_in[7];
    const float* ent_im = (const float*)d_in[8];
    float* out = (float*)d_out;
    char* ws   = (char*)d_ws;

    // byte layout (total 25,225,280 B == round-2/3 proven footprint)
    float* v_buf          = (float*)(ws);                    // 57,344 B
    float* sqU            = (float*)(ws + 57344);            // 448 B
    float* entU           = (float*)(ws + 57792);            // 1,664 B
    __hip_bfloat16* probs = (__hip_bfloat16*)(ws + 59456);   // 8,388,608 B
    float* part           = (float*)(ws + 8448064);          // 16,777,216 B

    k_pre<<<NB + 2, 256, 0, stream>>>(x, w_pre, b_pre, sq_re, sq_im, ent_re, ent_im,
                                      v_buf, sqU, entU);

    const int smem_bytes = (2 * SW_SIZE + NQ * 4 + (NQ - 1) * 32) * 4;
    (void)hipFuncSetAttribute((const void*)k_state,
                              hipFuncAttributeMaxDynamicSharedMemorySize, smem_bytes);
    k_state<<<NB, 1024, smem_bytes, stream>>>(v_buf, sqU, entU, probs);

    k_gemm_mfma<<<dim3(4, 16, SPLITK), 256, 0, stream>>>((const ushort*)probs, w_post, part);
    k_reduce<<<(NB * NH) / 256, 256, 0, stream>>>(part, b_post, out);
}

// Round 6
// 263.072 us; speedup vs baseline: 1.0087x; 1.0087x over previous
//
#include <hip/hip_runtime.h>
#include <hip/hip_bf16.h>
#include <math.h>

#define NQ 14
#define DIM 16384
#define NB 256
#define NH 1024
#define SPLITK 16
#define KCHUNK (DIM / SPLITK)   // 1024
#define BK 64

typedef __attribute__((ext_vector_type(8))) short bf16x8;
typedef __attribute__((ext_vector_type(4))) float f32x4;

// LDS swizzle for the state arrays: i + 5*(i>>5)  (injective, <=2-way banks)
#define SW(i) ((i) + 5 * ((i) >> 5))
#define SW_SIZE (DIM + 5 * (DIM / 32))   // 16384 + 2560 = 18944

// ---------------------------------------------------------------- QR helper
// Gram-Schmidt QR (double) -> Q with positive-real diag(R) == make_unitary(M)
template <int N>
__device__ void gs_qr(const float* Mre, const float* Mim, float* Uout) {
    double qre[N][N], qim[N][N];   // [col][row]
#pragma unroll
    for (int j = 0; j < N; j++) {
        double vr[N], vi[N];
#pragma unroll
        for (int r = 0; r < N; r++) { vr[r] = (double)Mre[r * N + j]; vi[r] = (double)Mim[r * N + j]; }
#pragma unroll
        for (int i = 0; i < N; i++) {
            if (i < j) {
                double rr = 0.0, ri = 0.0;
#pragma unroll
                for (int r = 0; r < N; r++) {
                    rr += qre[i][r] * vr[r] + qim[i][r] * vi[r];
                    ri += qre[i][r] * vi[r] - qim[i][r] * vr[r];
                }
#pragma unroll
                for (int r = 0; r < N; r++) {
                    vr[r] -= rr * qre[i][r] - ri * qim[i][r];
                    vi[r] -= rr * qim[i][r] + ri * qre[i][r];
                }
            }
        }
        double nn = 0.0;
#pragma unroll
        for (int r = 0; r < N; r++) nn += vr[r] * vr[r] + vi[r] * vi[r];
        double inv = 1.0 / sqrt(nn);
#pragma unroll
        for (int r = 0; r < N; r++) { qre[j][r] = vr[r] * inv; qim[j][r] = vi[r] * inv; }
    }
#pragma unroll
    for (int r = 0; r < N; r++)
#pragma unroll
        for (int j = 0; j < N; j++) {
            Uout[(r * N + j) * 2]     = (float)qre[j][r];
            Uout[(r * N + j) * 2 + 1] = (float)qim[j][r];
        }
}

// ---------------------------------------------------------------- kernel A
// blocks 0..NB-1: params = x @ w_pre^T + b_pre -> v vectors
// block NB: 2x2 QRs; block NB+1: 4x4 QRs
__global__ __launch_bounds__(256) void k_pre(const float* __restrict__ x,
                                             const float* __restrict__ w_pre,
                                             const float* __restrict__ b_pre,
                                             const float* __restrict__ sq_re,
                                             const float* __restrict__ sq_im,
                                             const float* __restrict__ ent_re,
                                             const float* __restrict__ ent_im,
                                             float* __restrict__ v_buf,
                                             float* __restrict__ sqU,
                                             float* __restrict__ entU) {
    const int b = blockIdx.x;
    const int t = threadIdx.x;
    if (b >= NB) {
        if (b == NB) {
            if (t < NQ) gs_qr<2>(sq_re + t * 4, sq_im + t * 4, sqU + t * 8);
        } else {
            if (t < NQ - 1) gs_qr<4>(ent_re + t * 16, ent_im + t * 16, entU + t * 32);
        }
        return;
    }
    __shared__ float red[28][4];

    float4 xs = ((const float4*)(x + (size_t)b * NH))[t];
    float acc[28];
#pragma unroll
    for (int j = 0; j < 28; j++) {
        float4 w = ((const float4*)(w_pre + (size_t)j * NH))[t];
        acc[j] = xs.x * w.x + xs.y * w.y + xs.z * w.z + xs.w * w.w;
    }
    int lane = t & 63, wv = t >> 6;
#pragma unroll
    for (int j = 0; j < 28; j++) {
        float a = acc[j];
#pragma unroll
        for (int o = 32; o > 0; o >>= 1) a += __shfl_down(a, o);
        if (lane == 0) red[j][wv] = a;
    }
    __syncthreads();
    if (t < NQ) {
        float p0 = red[2*t][0] + red[2*t][1] + red[2*t][2] + red[2*t][3] + b_pre[2*t];
        float p1 = red[2*t+1][0] + red[2*t+1][1] + red[2*t+1][2] + red[2*t+1][3] + b_pre[2*t+1];
        float c = cosf(p0 * 0.5f), s = sinf(p0 * 0.5f);
        float cp = cosf(p1), sp = sinf(p1);
        ((float4*)v_buf)[b * NQ + t] = make_float4(c, 0.f, cp * s, sp * s);
    }
}

// ---------------------------------------------------------------- kernel C
// Register-resident statevector: thread owns 16 amps (4 index bits).
// Ownership windows {0-3} -> {3-6} -> {6-9} -> {9-12} -> {10-13}; all 13
// two-qubit gates are register-local; 4 LDS transposes remap ownership.
// __launch_bounds__(1024, 4): 16-wave block => exactly 1 block/CU (the 153 KB
// dynamic LDS forces that anyway); raises VGPR cap 64 -> 128 so ar/ai stay in
// registers (R4: cap=64 spilled them -> 315 MB scratch HBM traffic, 103 us).
//
// apply gate at window position I (bits I, I+1 of the register index)
#define APPLY_GATE(I, GP) do {                                                \
    float gr_[16], gi_[16];                                                   \
    _Pragma("unroll")                                                         \
    for (int m_ = 0; m_ < 16; m_++) { gr_[m_] = (GP)[2*m_]; gi_[m_] = (GP)[2*m_+1]; } \
    _Pragma("unroll")                                                         \
    for (int g_ = 0; g_ < 4; g_++) {                                          \
        const int base_ = (I)==0 ? (g_<<2) : ((I)==1 ? ((g_&1)|((g_>>1)<<3)) : g_); \
        float xr_[4], xi_[4];                                                 \
        _Pragma("unroll")                                                     \
        for (int c_ = 0; c_ < 4; c_++) { xr_[c_] = ar[base_+(c_<<(I))]; xi_[c_] = ai[base_+(c_<<(I))]; } \
        _Pragma("unroll")                                                     \
        for (int r_ = 0; r_ < 4; r_++) {                                      \
            float nr_ = 0.f, ni_ = 0.f;                                       \
            _Pragma("unroll")                                                 \
            for (int c_ = 0; c_ < 4; c_++) {                                  \
                nr_ += gr_[r_*4+c_]*xr_[c_] - gi_[r_*4+c_]*xi_[c_];           \
                ni_ += gr_[r_*4+c_]*xi_[c_] + gi_[r_*4+c_]*xr_[c_];           \
            }                                                                 \
            ar[base_+(r_<<(I))] = nr_; ai[base_+(r_<<(I))] = ni_;             \
        }                                                                     \
    }                                                                         \
} while (0)

#define IDX_W0(r) (((t) << 4) | (r))
#define IDX_W1(r) (((t) & 7) | ((r) << 3) | (((t) >> 3) << 7))
#define IDX_W2(r) (((t) & 63) | ((r) << 6) | (((t) >> 6) << 10))
#define IDX_W3(r) (((t) & 511) | ((r) << 9) | (((t) >> 9) << 13))
#define IDX_W4(r) ((t) | ((r) << 10))

#define TRANSPOSE(IDX_OLD, IDX_NEW) do {                                      \
    _Pragma("unroll")                                                         \
    for (int r_ = 0; r_ < 16; r_++) {                                         \
        int o_ = SW(IDX_OLD(r_));                                             \
        sre[o_] = ar[r_]; simg[o_] = ai[r_];                                  \
    }                                                                         \
    __syncthreads();                                                          \
    _Pragma("unroll")                                                         \
    for (int r_ = 0; r_ < 16; r_++) {                                         \
        int n_ = SW(IDX_NEW(r_));                                             \
        ar[r_] = sre[n_]; ai[r_] = simg[n_];                                  \
    }                                                                         \
} while (0)

extern __shared__ float smem[];
__global__ __launch_bounds__(1024, 4) void k_state(const float* __restrict__ v_buf,
                                                   const float* __restrict__ sqU,
                                                   const float* __restrict__ entU,
                                                   __hip_bfloat16* __restrict__ probs) {
    const int b = blockIdx.x, t = threadIdx.x;
    float* sre  = smem;                       // SW_SIZE
    float* simg = smem + SW_SIZE;             // SW_SIZE
    float* wloc = smem + 2 * SW_SIZE;         // 14*4
    float* g2   = wloc + NQ * 4;              // 13*32

    if (t < (NQ - 1) * 32) g2[t] = entU[t];
    if (t < NQ) {
        // w_q = U_q v_q  (fused single-qubit gates)
        float4 v = ((const float4*)v_buf)[b * NQ + t];
        const float* u = sqU + t * 8;
        float w0r = u[0]*v.x - u[1]*v.y + u[2]*v.z - u[3]*v.w;
        float w0i = u[0]*v.y + u[1]*v.x + u[2]*v.w + u[3]*v.z;
        float w1r = u[4]*v.x - u[5]*v.y + u[6]*v.z - u[7]*v.w;
        float w1i = u[4]*v.y + u[5]*v.x + u[6]*v.w + u[7]*v.z;
        wloc[t*4+0] = w0r; wloc[t*4+1] = w0i; wloc[t*4+2] = w1r; wloc[t*4+3] = w1i;
    }
    __syncthreads();

    // ---- initial product state, ownership W0 (bits 0..3 in registers)
    float ar[16], ai[16];
    {
        float cr = 1.f, ci = 0.f;       // product over qubits 4..13 (bits of t)
#pragma unroll
        for (int q = 4; q < 14; q++) {
            int bit = (t >> (q - 4)) & 1;
            float br = wloc[q*4 + 2*bit], bi = wloc[q*4 + 2*bit + 1];
            float nr = cr*br - ci*bi, ni = cr*bi + ci*br;
            cr = nr; ci = ni;
        }
        float p01r[4], p01i[4], p23r[4], p23i[4];
#pragma unroll
        for (int j = 0; j < 4; j++) {
            int b0 = j & 1, b1 = j >> 1;
            float a0r = wloc[0*4 + 2*b0], a0i = wloc[0*4 + 2*b0 + 1];
            float a1r = wloc[1*4 + 2*b1], a1i = wloc[1*4 + 2*b1 + 1];
            p01r[j] = a0r*a1r - a0i*a1i; p01i[j] = a0r*a1i + a0i*a1r;
            float a2r = wloc[2*4 + 2*b0], a2i = wloc[2*4 + 2*b0 + 1];
            float a3r = wloc[3*4 + 2*b1], a3i = wloc[3*4 + 2*b1 + 1];
            p23r[j] = a2r*a3r - a2i*a3i; p23i[j] = a2r*a3i + a2i*a3r;
        }
#pragma unroll
        for (int r = 0; r < 16; r++) {
            int lo = r & 3, hi2 = r >> 2;
            float tr = cr*p01r[lo] - ci*p01i[lo];
            float ti = cr*p01i[lo] + ci*p01r[lo];
            ar[r] = tr*p23r[hi2] - ti*p23i[hi2];
            ai[r] = tr*p23i[hi2] + ti*p23r[hi2];
        }
    }

    // ---- W0 {0,1,2,3}: gates 0,1,2
    APPLY_GATE(0, g2 + 0*32);
    APPLY_GATE(1, g2 + 1*32);
    APPLY_GATE(2, g2 + 2*32);
    TRANSPOSE(IDX_W0, IDX_W1);
    // ---- W1 {3,4,5,6}: gates 3,4,5
    APPLY_GATE(0, g2 + 3*32);
    APPLY_GATE(1, g2 + 4*32);
    APPLY_GATE(2, g2 + 5*32);
    __syncthreads();                 // protect previous reads before rewrite
    TRANSPOSE(IDX_W1, IDX_W2);
    // ---- W2 {6,7,8,9}: gates 6,7,8
    APPLY_GATE(0, g2 + 6*32);
    APPLY_GATE(1, g2 + 7*32);
    APPLY_GATE(2, g2 + 8*32);
    __syncthreads();
    TRANSPOSE(IDX_W2, IDX_W3);
    // ---- W3 {9,10,11,12}: gates 9,10,11
    APPLY_GATE(0, g2 + 9*32);
    APPLY_GATE(1, g2 + 10*32);
    APPLY_GATE(2, g2 + 11*32);
    __syncthreads();
    TRANSPOSE(IDX_W3, IDX_W4);
    // ---- W4 {10,11,12,13}: gate 12 at position (2,3)
    APPLY_GATE(2, g2 + 12*32);

    // ---- probs, ownership W4: idx = t | (r<<10)
#pragma unroll
    for (int r = 0; r < 16; r++) {
        float pr = ar[r]*ar[r] + ai[r]*ai[r];
        probs[(size_t)b * DIM + (r << 10) + t] = __float2bfloat16(pr);
    }
}

// ---------------------------------------------------------------- kernel D
// bf16 MFMA GEMM: part[z] = probs[bf16] @ w_post^T (B f32 -> bf16 in staging)
// 64x64 tile, BK=64, 4 waves (2x2), wave tile 32x32, split-K=16.
// grid (4,16,16) = 1024 blocks = 4 blocks/CU for memory-latency overlap.
__global__ __launch_bounds__(256) void k_gemm_mfma(const ushort* __restrict__ A,
                                                   const float* __restrict__ Bw,
                                                   float* __restrict__ part) {
    __shared__ ushort As[64 * 64];
    __shared__ ushort Bs[64 * 64];
    const int t = threadIdx.x;
    const int l = t & 63, wid = t >> 6;             // 4 waves
    const int wr = wid >> 1, wc = wid & 1;          // 2 x 2 waves
    const int bm0 = blockIdx.x * 64;
    const int hn0 = blockIdx.y * 64;
    const int k0  = blockIdx.z * KCHUNK;

    f32x4 acc[2][2];
#pragma unroll
    for (int m = 0; m < 2; m++)
#pragma unroll
        for (int n = 0; n < 2; n++) acc[m][n] = (f32x4){0.f, 0.f, 0.f, 0.f};

    const int srow = t >> 3;            // 0..31 (B staging row within issue)
    const int scol = (t & 7) * 8;       // staging col (elems)
    const int alr  = l >> 3;            // lane row within 8-row chunk
    const int alc  = (l & 7) * 8;       // lane col (elems)

    for (int kc = 0; kc < KCHUNK; kc += BK) {
        const int kbase = k0 + kc;
        // ---- A: bf16 via global_load_lds (16B/lane), 8 wave-issues of 8 rows
#pragma unroll
        for (int i = 0; i < 2; i++) {
            const int r0 = (i * 4 + wid) * 8;       // wave-uniform row base
            const ushort* gsrc = A + (size_t)(bm0 + r0 + alr) * DIM + kbase + alc;
            __builtin_amdgcn_global_load_lds(
                (const __attribute__((address_space(1))) unsigned int*)gsrc,
                (__attribute__((address_space(3))) unsigned int*)&As[r0 * 64],
                16, 0, 0);
        }
        // ---- B: f32 load -> bf16 cvt -> ds_write_b128, 2 issues x 32 rows
#pragma unroll
        for (int i = 0; i < 2; i++) {
            const int r = i * 32 + srow;
            const float* bsrc = Bw + (size_t)(hn0 + r) * DIM + kbase + scol;
            float4 b0 = *(const float4*)(bsrc);
            float4 b1 = *(const float4*)(bsrc + 4);
            union { ushort u[8]; bf16x8 v; } pk;
            __hip_bfloat16 h;
            h = __float2bfloat16(b0.x); pk.u[0] = *(ushort*)&h;
            h = __float2bfloat16(b0.y); pk.u[1] = *(ushort*)&h;
            h = __float2bfloat16(b0.z); pk.u[2] = *(ushort*)&h;
            h = __float2bfloat16(b0.w); pk.u[3] = *(ushort*)&h;
            h = __float2bfloat16(b1.x); pk.u[4] = *(ushort*)&h;
            h = __float2bfloat16(b1.y); pk.u[5] = *(ushort*)&h;
            h = __float2bfloat16(b1.z); pk.u[6] = *(ushort*)&h;
            h = __float2bfloat16(b1.w); pk.u[7] = *(ushort*)&h;
            *(bf16x8*)&Bs[r * 64 + scol] = pk.v;
        }
        __syncthreads();   // drains vmcnt (global_load_lds) + lgkmcnt (ds_write)
        // ---- compute: 2 k-steps of 32, 4 MFMAs per wave per k-step
#pragma unroll
        for (int kk = 0; kk < 2; kk++) {
            const int kcol = kk * 32 + (l >> 4) * 8;
            bf16x8 a[2], bb[2];
#pragma unroll
            for (int m = 0; m < 2; m++)
                a[m] = *(const bf16x8*)&As[(wr * 32 + m * 16 + (l & 15)) * 64 + kcol];
#pragma unroll
            for (int n = 0; n < 2; n++)
                bb[n] = *(const bf16x8*)&Bs[(wc * 32 + n * 16 + (l & 15)) * 64 + kcol];
#pragma unroll
            for (int m = 0; m < 2; m++)
#pragma unroll
                for (int n = 0; n < 2; n++)
                    acc[m][n] = __builtin_amdgcn_mfma_f32_16x16x32_bf16(
                        a[m], bb[n], acc[m][n], 0, 0, 0);
        }
        __syncthreads();
    }
    // ---- write f32 partials; C/D layout: col = lane&15, row = (lane>>4)*4 + j
    float* dst = part + (size_t)blockIdx.z * (NB * NH);
#pragma unroll
    for (int m = 0; m < 2; m++) {
        const int row = bm0 + wr * 32 + m * 16 + (l >> 4) * 4;
#pragma unroll
        for (int n = 0; n < 2; n++) {
            const int col = hn0 + wc * 32 + n * 16 + (l & 15);
#pragma unroll
            for (int j = 0; j < 4; j++)
                dst[(size_t)(row + j) * NH + col] = acc[m][n][j];
        }
    }
}

__global__ __launch_bounds__(256) void k_reduce(const float* __restrict__ part,
                                                const float* __restrict__ b_post,
                                                float* __restrict__ out) {
    int i = blockIdx.x * 256 + threadIdx.x;   // 0..262143
    float s = b_post[i & (NH - 1)];
#pragma unroll
    for (int z = 0; z < SPLITK; z++) s += part[(size_t)z * (NB * NH) + i];
    out[i] = s;
}

// ---------------------------------------------------------------- launch
extern "C" void kernel_launch(void* const* d_in, const int* in_sizes, int n_in,
                              void* d_out, int out_size, void* d_ws, size_t ws_size,
                              hipStream_t stream) {
    const float* x      = (const float*)d_in[0];
    const float* w_pre  = (const float*)d_in[1];
    const float* b_pre  = (const float*)d_in[2];
    const float* w_post = (const float*)d_in[3];
    const float* b_post = (const float*)d_in[4];
    const float* sq_re  = (const float*)d_in[5];
    const float* sq_im  = (const float*)d_in[6];
    const float* ent_re = (const float*)d_in[7];
    const float* ent_im = (const float*)d_in[8];
    float* out = (float*)d_out;
    char* ws   = (char*)d_ws;

    // byte layout (total 25,225,280 B == round-2/3 proven footprint)
    float* v_buf          = (float*)(ws);                    // 57,344 B
    float* sqU            = (float*)(ws + 57344);            // 448 B
    float* entU           = (float*)(ws + 57792);            // 1,664 B
    __hip_bfloat16* probs = (__hip_bfloat16*)(ws + 59456);   // 8,388,608 B
    float* part           = (float*)(ws + 8448064);          // 16,777,216 B

    k_pre<<<NB + 2, 256, 0, stream>>>(x, w_pre, b_pre, sq_re, sq_im, ent_re, ent_im,
                                      v_buf, sqU, entU);

    const int smem_bytes = (2 * SW_SIZE + NQ * 4 + (NQ - 1) * 32) * 4;
    (void)hipFuncSetAttribute((const void*)k_state,
                              hipFuncAttributeMaxDynamicSharedMemorySize, smem_bytes);
    k_state<<<NB, 1024, smem_bytes, stream>>>(v_buf, sqU, entU, probs);

    k_gemm_mfma<<<dim3(4, 16, SPLITK), 256, 0, stream>>>((const ushort*)probs, w_post, part);
    k_reduce<<<(NB * NH) / 256, 256, 0, stream>>>(part, b_post, out);
}

// Round 12
// 192.911 us; speedup vs baseline: 1.3756x; 1.3637x over previous
//
#include <hip/hip_runtime.h>
#include <hip/hip_bf16.h>
#include <math.h>

#define NQ 14
#define DIM 16384
#define NB 256
#define NH 1024
#define SPLITK 16
#define KCHUNK (DIM / SPLITK)   // 1024
#define BK 64

typedef __attribute__((ext_vector_type(8))) short bf16x8;
typedef __attribute__((ext_vector_type(4))) float f32x4;

// LDS swizzle for the state arrays: i + 5*(i>>5)  (injective, <=2-way banks)
#define SW(i) ((i) + 5 * ((i) >> 5))
#define SW_SIZE (DIM + 5 * (DIM / 32))   // 16384 + 2560 = 18944

// ---------------------------------------------------------------- QR helper
// Gram-Schmidt QR (double) -> Q with positive-real diag(R) == make_unitary(M)
template <int N>
__device__ void gs_qr(const float* Mre, const float* Mim, float* Uout) {
    double qre[N][N], qim[N][N];   // [col][row]
#pragma unroll
    for (int j = 0; j < N; j++) {
        double vr[N], vi[N];
#pragma unroll
        for (int r = 0; r < N; r++) { vr[r] = (double)Mre[r * N + j]; vi[r] = (double)Mim[r * N + j]; }
#pragma unroll
        for (int i = 0; i < N; i++) {
            if (i < j) {
                double rr = 0.0, ri = 0.0;
#pragma unroll
                for (int r = 0; r < N; r++) {
                    rr += qre[i][r] * vr[r] + qim[i][r] * vi[r];
                    ri += qre[i][r] * vi[r] - qim[i][r] * vr[r];
                }
#pragma unroll
                for (int r = 0; r < N; r++) {
                    vr[r] -= rr * qre[i][r] - ri * qim[i][r];
                    vi[r] -= rr * qim[i][r] + ri * qre[i][r];
                }
            }
        }
        double nn = 0.0;
#pragma unroll
        for (int r = 0; r < N; r++) nn += vr[r] * vr[r] + vi[r] * vi[r];
        double inv = 1.0 / sqrt(nn);
#pragma unroll
        for (int r = 0; r < N; r++) { qre[j][r] = vr[r] * inv; qim[j][r] = vi[r] * inv; }
    }
#pragma unroll
    for (int r = 0; r < N; r++)
#pragma unroll
        for (int j = 0; j < N; j++) {
            Uout[(r * N + j) * 2]     = (float)qre[j][r];
            Uout[(r * N + j) * 2 + 1] = (float)qim[j][r];
        }
}

// ---------------------------------------------------------------- kernel A
// blocks 0..NB-1: params = x @ w_pre^T + b_pre -> v vectors
// block NB: 2x2 QRs; block NB+1: 4x4 QRs
__global__ __launch_bounds__(256) void k_pre(const float* __restrict__ x,
                                             const float* __restrict__ w_pre,
                                             const float* __restrict__ b_pre,
                                             const float* __restrict__ sq_re,
                                             const float* __restrict__ sq_im,
                                             const float* __restrict__ ent_re,
                                             const float* __restrict__ ent_im,
                                             float* __restrict__ v_buf,
                                             float* __restrict__ sqU,
                                             float* __restrict__ entU) {
    const int b = blockIdx.x;
    const int t = threadIdx.x;
    if (b >= NB) {
        if (b == NB) {
            if (t < NQ) gs_qr<2>(sq_re + t * 4, sq_im + t * 4, sqU + t * 8);
        } else {
            if (t < NQ - 1) gs_qr<4>(ent_re + t * 16, ent_im + t * 16, entU + t * 32);
        }
        return;
    }
    __shared__ float red[28][4];

    float4 xs = ((const float4*)(x + (size_t)b * NH))[t];
    float acc[28];
#pragma unroll
    for (int j = 0; j < 28; j++) {
        float4 w = ((const float4*)(w_pre + (size_t)j * NH))[t];
        acc[j] = xs.x * w.x + xs.y * w.y + xs.z * w.z + xs.w * w.w;
    }
    int lane = t & 63, wv = t >> 6;
#pragma unroll
    for (int j = 0; j < 28; j++) {
        float a = acc[j];
#pragma unroll
        for (int o = 32; o > 0; o >>= 1) a += __shfl_down(a, o);
        if (lane == 0) red[j][wv] = a;
    }
    __syncthreads();
    if (t < NQ) {
        float p0 = red[2*t][0] + red[2*t][1] + red[2*t][2] + red[2*t][3] + b_pre[2*t];
        float p1 = red[2*t+1][0] + red[2*t+1][1] + red[2*t+1][2] + red[2*t+1][3] + b_pre[2*t+1];
        float c = cosf(p0 * 0.5f), s = sinf(p0 * 0.5f);
        float cp = cosf(p1), sp = sinf(p1);
        ((float4*)v_buf)[b * NQ + t] = make_float4(c, 0.f, cp * s, sp * s);
    }
}

// ---------------------------------------------------------------- kernel C
// Register-resident statevector: thread owns 16 amps (4 index bits).
// Ownership windows {0-3} -> {3-6} -> {6-9} -> {9-12} -> {10-13}; all 13
// two-qubit gates are register-local; 4 LDS transposes remap ownership.
//
// R6 lesson: VGPR cap stayed 64 regardless of __launch_bounds__ 2nd arg, and
// 32 live amps + 32 gate coeffs spilled (315 MB scratch HBM traffic, 103 us).
// Fix: gate coefficients are wave-uniform -> read them straight from the
// entU kernel-arg pointer with compile-time offsets. Uniform address =>
// compiler emits s_load into SGPRs; v_fma reads 1 SGPR operand legally.
// Peak live VGPRs ~= 32 amps + 8 gather + temps < 64 => no spills.
//
// apply gate at window position I (bits I, I+1 of the register index);
// GP = uniform global pointer to the 4x4 complex gate (row-major, re/im pairs)
#define APPLY_GATE(I, GP) do {                                                \
    _Pragma("unroll")                                                         \
    for (int g_ = 0; g_ < 4; g_++) {                                          \
        const int base_ = (I)==0 ? (g_<<2) : ((I)==1 ? ((g_&1)|((g_>>1)<<3)) : g_); \
        float xr_[4], xi_[4];                                                 \
        _Pragma("unroll")                                                     \
        for (int c_ = 0; c_ < 4; c_++) { xr_[c_] = ar[base_+(c_<<(I))]; xi_[c_] = ai[base_+(c_<<(I))]; } \
        _Pragma("unroll")                                                     \
        for (int r_ = 0; r_ < 4; r_++) {                                      \
            float nr_ = 0.f, ni_ = 0.f;                                       \
            _Pragma("unroll")                                                 \
            for (int c_ = 0; c_ < 4; c_++) {                                  \
                const float grc_ = (GP)[(r_*4+c_)*2];                         \
                const float gic_ = (GP)[(r_*4+c_)*2+1];                       \
                nr_ += grc_*xr_[c_] - gic_*xi_[c_];                           \
                ni_ += grc_*xi_[c_] + gic_*xr_[c_];                           \
            }                                                                 \
            ar[base_+(r_<<(I))] = nr_; ai[base_+(r_<<(I))] = ni_;             \
        }                                                                     \
    }                                                                         \
} while (0)

#define IDX_W0(r) (((t) << 4) | (r))
#define IDX_W1(r) (((t) & 7) | ((r) << 3) | (((t) >> 3) << 7))
#define IDX_W2(r) (((t) & 63) | ((r) << 6) | (((t) >> 6) << 10))
#define IDX_W3(r) (((t) & 511) | ((r) << 9) | (((t) >> 9) << 13))
#define IDX_W4(r) ((t) | ((r) << 10))

#define TRANSPOSE(IDX_OLD, IDX_NEW) do {                                      \
    _Pragma("unroll")                                                         \
    for (int r_ = 0; r_ < 16; r_++) {                                         \
        int o_ = SW(IDX_OLD(r_));                                             \
        sre[o_] = ar[r_]; simg[o_] = ai[r_];                                  \
    }                                                                         \
    __syncthreads();                                                          \
    _Pragma("unroll")                                                         \
    for (int r_ = 0; r_ < 16; r_++) {                                         \
        int n_ = SW(IDX_NEW(r_));                                             \
        ar[r_] = sre[n_]; ai[r_] = simg[n_];                                  \
    }                                                                         \
} while (0)

extern __shared__ float smem[];
__global__ __launch_bounds__(1024) void k_state(const float* __restrict__ v_buf,
                                                const float* __restrict__ sqU,
                                                const float* __restrict__ entU,
                                                __hip_bfloat16* __restrict__ probs) {
    const int b = blockIdx.x, t = threadIdx.x;
    float* sre  = smem;                       // SW_SIZE
    float* simg = smem + SW_SIZE;             // SW_SIZE
    float* wloc = smem + 2 * SW_SIZE;         // 14*4

    if (t < NQ) {
        // w_q = U_q v_q  (fused single-qubit gates)
        float4 v = ((const float4*)v_buf)[b * NQ + t];
        const float* u = sqU + t * 8;
        float w0r = u[0]*v.x - u[1]*v.y + u[2]*v.z - u[3]*v.w;
        float w0i = u[0]*v.y + u[1]*v.x + u[2]*v.w + u[3]*v.z;
        float w1r = u[4]*v.x - u[5]*v.y + u[6]*v.z - u[7]*v.w;
        float w1i = u[4]*v.y + u[5]*v.x + u[6]*v.w + u[7]*v.z;
        wloc[t*4+0] = w0r; wloc[t*4+1] = w0i; wloc[t*4+2] = w1r; wloc[t*4+3] = w1i;
    }
    __syncthreads();

    // ---- initial product state, ownership W0 (bits 0..3 in registers)
    float ar[16], ai[16];
    {
        float cr = 1.f, ci = 0.f;       // product over qubits 4..13 (bits of t)
#pragma unroll
        for (int q = 4; q < 14; q++) {
            int bit = (t >> (q - 4)) & 1;
            float br = wloc[q*4 + 2*bit], bi = wloc[q*4 + 2*bit + 1];
            float nr = cr*br - ci*bi, ni = cr*bi + ci*br;
            cr = nr; ci = ni;
        }
        float p01r[4], p01i[4], p23r[4], p23i[4];
#pragma unroll
        for (int j = 0; j < 4; j++) {
            int b0 = j & 1, b1 = j >> 1;
            float a0r = wloc[0*4 + 2*b0], a0i = wloc[0*4 + 2*b0 + 1];
            float a1r = wloc[1*4 + 2*b1], a1i = wloc[1*4 + 2*b1 + 1];
            p01r[j] = a0r*a1r - a0i*a1i; p01i[j] = a0r*a1i + a0i*a1r;
            float a2r = wloc[2*4 + 2*b0], a2i = wloc[2*4 + 2*b0 + 1];
            float a3r = wloc[3*4 + 2*b1], a3i = wloc[3*4 + 2*b1 + 1];
            p23r[j] = a2r*a3r - a2i*a3i; p23i[j] = a2r*a3i + a2i*a3r;
        }
#pragma unroll
        for (int r = 0; r < 16; r++) {
            int lo = r & 3, hi2 = r >> 2;
            float tr = cr*p01r[lo] - ci*p01i[lo];
            float ti = cr*p01i[lo] + ci*p01r[lo];
            ar[r] = tr*p23r[hi2] - ti*p23i[hi2];
            ai[r] = tr*p23i[hi2] + ti*p23r[hi2];
        }
    }

    // ---- W0 {0,1,2,3}: gates 0,1,2
    APPLY_GATE(0, entU + 0*32);
    APPLY_GATE(1, entU + 1*32);
    APPLY_GATE(2, entU + 2*32);
    TRANSPOSE(IDX_W0, IDX_W1);
    // ---- W1 {3,4,5,6}: gates 3,4,5
    APPLY_GATE(0, entU + 3*32);
    APPLY_GATE(1, entU + 4*32);
    APPLY_GATE(2, entU + 5*32);
    __syncthreads();                 // protect previous reads before rewrite
    TRANSPOSE(IDX_W1, IDX_W2);
    // ---- W2 {6,7,8,9}: gates 6,7,8
    APPLY_GATE(0, entU + 6*32);
    APPLY_GATE(1, entU + 7*32);
    APPLY_GATE(2, entU + 8*32);
    __syncthreads();
    TRANSPOSE(IDX_W2, IDX_W3);
    // ---- W3 {9,10,11,12}: gates 9,10,11
    APPLY_GATE(0, entU + 9*32);
    APPLY_GATE(1, entU + 10*32);
    APPLY_GATE(2, entU + 11*32);
    __syncthreads();
    TRANSPOSE(IDX_W3, IDX_W4);
    // ---- W4 {10,11,12,13}: gate 12 at position (2,3)
    APPLY_GATE(2, entU + 12*32);

    // ---- probs, ownership W4: idx = t | (r<<10)
#pragma unroll
    for (int r = 0; r < 16; r++) {
        float pr = ar[r]*ar[r] + ai[r]*ai[r];
        probs[(size_t)b * DIM + (r << 10) + t] = __float2bfloat16(pr);
    }
}

// ---------------------------------------------------------------- kernel D
// bf16 MFMA GEMM (R3-measured config: 54.9 us): part[z] = probs @ w_post^T
// 128x128 tile, BK=64, 8 waves (2x4), wave tile 64x32, split-K=16,
// grid (2,8,16) = 256 blocks.
__global__ __launch_bounds__(512) void k_gemm_mfma(const ushort* __restrict__ A,
                                                   const float* __restrict__ Bw,
                                                   float* __restrict__ part) {
    __shared__ ushort As[128 * 64];
    __shared__ ushort Bs[128 * 64];
    const int t = threadIdx.x;
    const int l = t & 63, wid = t >> 6;
    const int wr = wid >> 2, wc = wid & 3;          // 2 x 4 waves
    const int bm0 = blockIdx.x * 128;
    const int hn0 = blockIdx.y * 128;
    const int k0  = blockIdx.z * KCHUNK;

    f32x4 acc[4][2];
#pragma unroll
    for (int m = 0; m < 4; m++)
#pragma unroll
        for (int n = 0; n < 2; n++) acc[m][n] = (f32x4){0.f, 0.f, 0.f, 0.f};

    const int srow = t >> 3;            // 0..63 (B staging row within issue)
    const int scol = (t & 7) * 8;       // B staging col (elems)
    const int alr  = l >> 3;            // lane row within wave's 8-row chunk
    const int alc  = (l & 7) * 8;       // lane col (elems)

    for (int kc = 0; kc < KCHUNK; kc += BK) {
        const int kbase = k0 + kc;
        // ---- A: bf16 via global_load_lds (16B/lane), 2 issues x 64 rows
#pragma unroll
        for (int i = 0; i < 2; i++) {
            const int r0 = i * 64 + wid * 8;        // wave-uniform row base
            const ushort* gsrc = A + (size_t)(bm0 + r0 + alr) * DIM + kbase + alc;
            __builtin_amdgcn_global_load_lds(
                (const __attribute__((address_space(1))) unsigned int*)gsrc,
                (__attribute__((address_space(3))) unsigned int*)&As[r0 * 64],
                16, 0, 0);
        }
        // ---- B: f32 load -> bf16 cvt -> ds_write_b128, 2 issues x 64 rows
#pragma unroll
        for (int i = 0; i < 2; i++) {
            const int r = i * 64 + srow;
            const float* bsrc = Bw + (size_t)(hn0 + r) * DIM + kbase + scol;
            float4 b0 = *(const float4*)(bsrc);
            float4 b1 = *(const float4*)(bsrc + 4);
            union { ushort u[8]; bf16x8 v; } pk;
            __hip_bfloat16 h;
            h = __float2bfloat16(b0.x); pk.u[0] = *(ushort*)&h;
            h = __float2bfloat16(b0.y); pk.u[1] = *(ushort*)&h;
            h = __float2bfloat16(b0.z); pk.u[2] = *(ushort*)&h;
            h = __float2bfloat16(b0.w); pk.u[3] = *(ushort*)&h;
            h = __float2bfloat16(b1.x); pk.u[4] = *(ushort*)&h;
            h = __float2bfloat16(b1.y); pk.u[5] = *(ushort*)&h;
            h = __float2bfloat16(b1.z); pk.u[6] = *(ushort*)&h;
            h = __float2bfloat16(b1.w); pk.u[7] = *(ushort*)&h;
            *(bf16x8*)&Bs[r * 64 + scol] = pk.v;
        }
        __syncthreads();   // drains vmcnt (global_load_lds) + lgkmcnt (ds_write)
        // ---- compute: 2 k-steps of 32, 16 MFMAs per wave per iter
#pragma unroll
        for (int kk = 0; kk < 2; kk++) {
            const int kcol = kk * 32 + (l >> 4) * 8;
            bf16x8 a[4], b[2];
#pragma unroll
            for (int m = 0; m < 4; m++)
                a[m] = *(const bf16x8*)&As[(wr * 64 + m * 16 + (l & 15)) * 64 + kcol];
#pragma unroll
            for (int n = 0; n < 2; n++)
                b[n] = *(const bf16x8*)&Bs[(wc * 32 + n * 16 + (l & 15)) * 64 + kcol];
#pragma unroll
            for (int m = 0; m < 4; m++)
#pragma unroll
                for (int n = 0; n < 2; n++)
                    acc[m][n] = __builtin_amdgcn_mfma_f32_16x16x32_bf16(
                        a[m], b[n], acc[m][n], 0, 0, 0);
        }
        __syncthreads();
    }
    // ---- write f32 partials; C/D layout: col = lane&15, row = (lane>>4)*4 + j
    float* dst = part + (size_t)blockIdx.z * (NB * NH);
#pragma unroll
    for (int m = 0; m < 4; m++) {
        const int row = bm0 + wr * 64 + m * 16 + (l >> 4) * 4;
#pragma unroll
        for (int n = 0; n < 2; n++) {
            const int col = hn0 + wc * 32 + n * 16 + (l & 15);
#pragma unroll
            for (int j = 0; j < 4; j++)
                dst[(size_t)(row + j) * NH + col] = acc[m][n][j];
        }
    }
}

__global__ __launch_bounds__(256) void k_reduce(const float* __restrict__ part,
                                                const float* __restrict__ b_post,
                                                float* __restrict__ out) {
    int i = blockIdx.x * 256 + threadIdx.x;   // 0..262143
    float s = b_post[i & (NH - 1)];
#pragma unroll
    for (int z = 0; z < SPLITK; z++) s += part[(size_t)z * (NB * NH) + i];
    out[i] = s;
}

// ---------------------------------------------------------------- launch
extern "C" void kernel_launch(void* const* d_in, const int* in_sizes, int n_in,
                              void* d_out, int out_size, void* d_ws, size_t ws_size,
                              hipStream_t stream) {
    const float* x      = (const float*)d_in[0];
    const float* w_pre  = (const float*)d_in[1];
    const float* b_pre  = (const float*)d_in[2];
    const float* w_post = (const float*)d_in[3];
    const float* b_post = (const float*)d_in[4];
    const float* sq_re  = (const float*)d_in[5];
    const float* sq_im  = (const float*)d_in[6];
    const float* ent_re = (const float*)d_in[7];
    const float* ent_im = (const float*)d_in[8];
    float* out = (float*)d_out;
    char* ws   = (char*)d_ws;

    // byte layout (total 25,225,280 B == proven footprint)
    float* v_buf          = (float*)(ws);                    // 57,344 B
    float* sqU            = (float*)(ws + 57344);            // 448 B
    float* entU           = (float*)(ws + 57792);            // 1,664 B
    __hip_bfloat16* probs = (__hip_bfloat16*)(ws + 59456);   // 8,388,608 B
    float* part           = (float*)(ws + 8448064);          // 16,777,216 B

    k_pre<<<NB + 2, 256, 0, stream>>>(x, w_pre, b_pre, sq_re, sq_im, ent_re, ent_im,
                                      v_buf, sqU, entU);

    const int smem_bytes = (2 * SW_SIZE + NQ * 4) * 4;
    (void)hipFuncSetAttribute((const void*)k_state,
                              hipFuncAttributeMaxDynamicSharedMemorySize, smem_bytes);
    k_state<<<NB, 1024, smem_bytes, stream>>>(v_buf, sqU, entU, probs);

    k_gemm_mfma<<<dim3(2, 8, SPLITK), 512, 0, stream>>>((const ushort*)probs, w_post, part);
    k_reduce<<<(NB * NH) / 256, 256, 0, stream>>>(part, b_post, out);
}